// Round 1
// baseline (315.405 us; speedup 1.0000x reference)
//
#include <hip/hip_runtime.h>

#define BATCH 8
#define HH 64
#define WW 64
#define CC 256
#define KK 512
#define CH 7
#define CW 7
#define HW 4096            // HH*WW
#define CROPS_ELEMS (BATCH * KK * CH * CW * CC)   // 51,380,224
#define BOXES_ELEMS (BATCH * KK * 4)              // 16,384

// ---------------------------------------------------------------------------
// Kernel 1: per-batch top-512 (exact jax.lax.top_k semantics: descending
// score, ties -> lower index first) via in-LDS bitonic sort of 64-bit keys.
// key = (ordered_uint(score) << 12) | (4095 - index)
// Monotone float->uint: neg -> ~bits, pos -> bits|0x80000000. Higher key =
// higher score; among equal scores, lower index => larger (4095-index) =>
// sorts first in descending order. Matches XLA tie-breaking.
// ---------------------------------------------------------------------------
__global__ __launch_bounds__(1024) void topk_kernel(
    const float* __restrict__ scores,      // [B, 4096]
    const float* __restrict__ boxes,       // [B, 4096, 4]
    float* __restrict__ boxes_out,         // [B, 512, 4]
    float* __restrict__ idx_out)           // [B, 512] (as float values)
{
    __shared__ unsigned long long s[HW];
    const int b   = blockIdx.x;
    const int tid = threadIdx.x;

    for (int i = tid; i < HW; i += 1024) {
        unsigned int u = __float_as_uint(scores[b * HW + i]);
        u = (u & 0x80000000u) ? ~u : (u | 0x80000000u);
        s[i] = ((unsigned long long)u << 12) |
               (unsigned long long)(HW - 1 - i);
    }
    __syncthreads();

    // Bitonic sort, descending (largest key first).
    for (int k = 2; k <= HW; k <<= 1) {
        for (int j = k >> 1; j > 0; j >>= 1) {
            for (int i = tid; i < HW; i += 1024) {
                int ixj = i ^ j;
                if (ixj > i) {
                    unsigned long long a = s[i];
                    unsigned long long c = s[ixj];
                    bool desc = ((i & k) == 0);
                    if (desc ? (a < c) : (a > c)) { s[i] = c; s[ixj] = a; }
                }
            }
            __syncthreads();
        }
    }

    if (tid < KK) {
        unsigned long long key = s[tid];
        int idx = (HW - 1) - (int)(key & 0xFFFull);
        idx_out[b * KK + tid] = (float)idx;
        const float* bp = boxes + (size_t)(b * HW + idx) * 4;
        float* op = boxes_out + (size_t)(b * KK + tid) * 4;
        op[0] = bp[0]; op[1] = bp[1]; op[2] = bp[2]; op[3] = bp[3];
    }
}

// ---------------------------------------------------------------------------
// Kernel 2: crop_and_resize. One wave per output pixel (b,n,iy,ix); each lane
// owns 4 channels (float4). 4 coalesced 1KiB gathers + blend + 1KiB store.
// Coordinate math mirrors the reference elementwise ops exactly (no FMA
// contraction) because floor() boundaries are discontinuous under the
// clip-after-floor edge semantics.
// ---------------------------------------------------------------------------
__global__ __launch_bounds__(256) void crops_kernel(
    const float* __restrict__ fm,          // [B, 64, 64, 256]
    const float* __restrict__ sboxes,      // [B, 512, 4]
    float* __restrict__ out)               // [B, 512, 7, 7, 256]
{
    const int gtid = blockIdx.x * 256 + threadIdx.x;
    const int wave = gtid >> 6;            // global wave id: [0, 8*512*49)
    const int lane = threadIdx.x & 63;

    const int q  = wave % 49;              // iy*7 + ix
    const int bn = wave / 49;              // b*512 + n
    const int iy = q / 7;
    const int ix = q % 7;
    const int b  = bn >> 9;

    const float* bp = sboxes + (size_t)bn * 4;
    const float y1 = bp[0], x1 = bp[1], y2 = bp[2], x2 = bp[3];

    const float fy = (float)iy / 6.0f;
    const float fx = (float)ix / 6.0f;
    // y = (y1 + fy*(y2-y1)) * 63 — exact elementwise rounding, no contraction
    const float y = __fmul_rn(__fadd_rn(y1, __fmul_rn(fy, __fsub_rn(y2, y1))), 63.0f);
    const float x = __fmul_rn(__fadd_rn(x1, __fmul_rn(fx, __fsub_rn(x2, x1))), 63.0f);

    const float y0f = floorf(y);
    const float x0f = floorf(x);
    const float wy = y - y0f;
    const float wx = x - x0f;

    int y0 = (int)y0f; y0 = min(max(y0, 0), HH - 1);
    int x0 = (int)x0f; x0 = min(max(x0, 0), WW - 1);
    const int y1i = min(y0 + 1, HH - 1);
    const int x1i = min(x0 + 1, WW - 1);

    const size_t base = (size_t)b * (HH * WW * CC);
    const int c0 = lane * 4;
    const float4 v00 = *(const float4*)(fm + base + (size_t)(y0  * WW + x0 ) * CC + c0);
    const float4 v01 = *(const float4*)(fm + base + (size_t)(y0  * WW + x1i) * CC + c0);
    const float4 v10 = *(const float4*)(fm + base + (size_t)(y1i * WW + x0 ) * CC + c0);
    const float4 v11 = *(const float4*)(fm + base + (size_t)(y1i * WW + x1i) * CC + c0);

    const float owx = 1.0f - wx;
    const float owy = 1.0f - wy;

    float4 r;
    {
        float t, bo;
        t  = v00.x * owx + v01.x * wx;  bo = v10.x * owx + v11.x * wx;  r.x = t * owy + bo * wy;
        t  = v00.y * owx + v01.y * wx;  bo = v10.y * owx + v11.y * wx;  r.y = t * owy + bo * wy;
        t  = v00.z * owx + v01.z * wx;  bo = v10.z * owx + v11.z * wx;  r.z = t * owy + bo * wy;
        t  = v00.w * owx + v01.w * wx;  bo = v10.w * owx + v11.w * wx;  r.w = t * owy + bo * wy;
    }

    *(float4*)(out + (size_t)(bn * 49 + q) * CC + c0) = r;
}

extern "C" void kernel_launch(void* const* d_in, const int* in_sizes, int n_in,
                              void* d_out, int out_size, void* d_ws, size_t ws_size,
                              hipStream_t stream) {
    const float* feature_map = (const float*)d_in[0];   // 8*64*64*256
    const float* boxes       = (const float*)d_in[1];   // 8*64*64*4
    const float* rpn_loss    = (const float*)d_in[2];   // 8*64*64

    float* crops_out = (float*)d_out;                       // 51,380,224
    float* boxes_out = crops_out + CROPS_ELEMS;             // 16,384
    float* idx_out   = boxes_out + BOXES_ELEMS;             // 4,096

    topk_kernel<<<BATCH, 1024, 0, stream>>>(rpn_loss, boxes, boxes_out, idx_out);

    const int total_waves  = BATCH * KK * CH * CW;          // 200,704
    const int blocks       = total_waves / 4;               // 50,176 (256 thr = 4 waves)
    crops_kernel<<<blocks, 256, 0, stream>>>(feature_map, boxes_out, crops_out);
}

// Round 2
// 273.439 us; speedup vs baseline: 1.1535x; 1.1535x over previous
//
#include <hip/hip_runtime.h>

#define BATCH 8
#define HH 64
#define WW 64
#define CC 256
#define KK 512
#define CH 7
#define CW 7
#define HW 4096            // HH*WW
#define CROPS_ELEMS (BATCH * KK * CH * CW * CC)   // 51,380,224
#define BOXES_ELEMS (BATCH * KK * 4)              // 16,384

using f4 = __attribute__((ext_vector_type(4))) float;

// ---------------------------------------------------------------------------
// Kernel 1: per-batch top-512 by RANK SELECTION (no sort, no cross-block
// sync). key = (ordered_uint(score) << 12) | (4095 - index) is unique per
// element, so rank(i) = #{keys > key_i} is the exact descending-sort position
// with jax.lax.top_k tie semantics (equal score -> lower index first).
// Grid: 64 blocks per batch x 8 batches; each block stages the batch's 4096
// keys in LDS and ranks 64 elements (scan split 4-ways per element).
// ---------------------------------------------------------------------------
__global__ __launch_bounds__(256) void rank_topk_kernel(
    const float* __restrict__ scores,      // [B, 4096]
    const float* __restrict__ boxes,       // [B, 4096, 4]
    float* __restrict__ boxes_out,         // [B, 512, 4]
    float* __restrict__ idx_out)           // [B, 512] (as float values)
{
    __shared__ unsigned long long keys[HW];   // 32 KB
    __shared__ int cnt[64];

    const int b     = blockIdx.x >> 6;        // batch
    const int chunk = blockIdx.x & 63;        // which 64-element slice we rank
    const int tid   = threadIdx.x;

    // Stage all 4096 keys of this batch into LDS (coalesced, 16/thread).
    for (int i = tid; i < HW; i += 256) {
        unsigned int u = __float_as_uint(scores[b * HW + i]);
        u = (u & 0x80000000u) ? ~u : (u | 0x80000000u);
        keys[i] = ((unsigned long long)u << 12) |
                  (unsigned long long)(HW - 1 - i);
    }
    if (tid < 64) cnt[tid] = 0;
    __syncthreads();

    // Element e = chunk*64 + (tid&63); this thread scans quarter (tid>>6).
    const int e_local = tid & 63;
    const int e       = chunk * 64 + e_local;
    const unsigned long long mine = keys[e];
    const int seg = (tid >> 6) * (HW / 4);

    int c = 0;
    #pragma unroll 8
    for (int j = 0; j < HW / 4; ++j) {
        c += (keys[seg + j] > mine) ? 1 : 0;
    }
    atomicAdd(&cnt[e_local], c);
    __syncthreads();

    if (tid < 64) {
        const int r = cnt[tid];                 // exact descending rank
        if (r < KK) {
            const int i = chunk * 64 + tid;     // original flat index
            idx_out[b * KK + r] = (float)i;
            const float* bp = boxes + (size_t)(b * HW + i) * 4;
            float* op = boxes_out + (size_t)(b * KK + r) * 4;
            op[0] = bp[0]; op[1] = bp[1]; op[2] = bp[2]; op[3] = bp[3];
        }
    }
}

// ---------------------------------------------------------------------------
// Kernel 2: crop_and_resize. One wave per output pixel (b,n,iy,ix); each lane
// owns 4 channels (f4). 4 coalesced 1KiB gathers + blend + 1KiB NT store.
// NT store keeps the 33.5 MB feature map resident in L2 instead of letting
// the 205 MB streaming output evict it. Coordinate math mirrors the
// reference's elementwise rounding exactly (no FMA contraction) because
// floor() boundaries are discontinuous under clip-after-floor semantics.
// ---------------------------------------------------------------------------
__global__ __launch_bounds__(256) void crops_kernel(
    const float* __restrict__ fm,          // [B, 64, 64, 256]
    const float* __restrict__ sboxes,      // [B, 512, 4]
    float* __restrict__ out)               // [B, 512, 7, 7, 256]
{
    const int gtid = blockIdx.x * 256 + threadIdx.x;
    const int wave = gtid >> 6;            // global wave id: [0, 8*512*49)
    const int lane = threadIdx.x & 63;

    const int q  = wave % 49;              // iy*7 + ix
    const int bn = wave / 49;              // b*512 + n
    const int iy = q / 7;
    const int ix = q % 7;
    const int b  = bn >> 9;

    const float* bp = sboxes + (size_t)bn * 4;
    const float y1 = bp[0], x1 = bp[1], y2 = bp[2], x2 = bp[3];

    const float fy = (float)iy / 6.0f;
    const float fx = (float)ix / 6.0f;
    // y = (y1 + fy*(y2-y1)) * 63 — exact elementwise rounding, no contraction
    const float y = __fmul_rn(__fadd_rn(y1, __fmul_rn(fy, __fsub_rn(y2, y1))), 63.0f);
    const float x = __fmul_rn(__fadd_rn(x1, __fmul_rn(fx, __fsub_rn(x2, x1))), 63.0f);

    const float y0f = floorf(y);
    const float x0f = floorf(x);
    const float wy = y - y0f;
    const float wx = x - x0f;

    int y0 = (int)y0f; y0 = min(max(y0, 0), HH - 1);
    int x0 = (int)x0f; x0 = min(max(x0, 0), WW - 1);
    const int y1i = min(y0 + 1, HH - 1);
    const int x1i = min(x0 + 1, WW - 1);

    const size_t base = (size_t)b * (HH * WW * CC);
    const int c0 = lane * 4;
    const f4 v00 = *(const f4*)(fm + base + (size_t)(y0  * WW + x0 ) * CC + c0);
    const f4 v01 = *(const f4*)(fm + base + (size_t)(y0  * WW + x1i) * CC + c0);
    const f4 v10 = *(const f4*)(fm + base + (size_t)(y1i * WW + x0 ) * CC + c0);
    const f4 v11 = *(const f4*)(fm + base + (size_t)(y1i * WW + x1i) * CC + c0);

    const float owx = 1.0f - wx;
    const float owy = 1.0f - wy;

    f4 r;
    #pragma unroll
    for (int k = 0; k < 4; ++k) {
        float t  = v00[k] * owx + v01[k] * wx;
        float bo = v10[k] * owx + v11[k] * wx;
        r[k] = t * owy + bo * wy;
    }

    __builtin_nontemporal_store(r, (f4*)(out + (size_t)(bn * 49 + q) * CC + c0));
}

extern "C" void kernel_launch(void* const* d_in, const int* in_sizes, int n_in,
                              void* d_out, int out_size, void* d_ws, size_t ws_size,
                              hipStream_t stream) {
    const float* feature_map = (const float*)d_in[0];   // 8*64*64*256
    const float* boxes       = (const float*)d_in[1];   // 8*64*64*4
    const float* rpn_loss    = (const float*)d_in[2];   // 8*64*64

    float* crops_out = (float*)d_out;                       // 51,380,224
    float* boxes_out = crops_out + CROPS_ELEMS;             // 16,384
    float* idx_out   = boxes_out + BOXES_ELEMS;             // 4,096

    rank_topk_kernel<<<BATCH * 64, 256, 0, stream>>>(rpn_loss, boxes, boxes_out, idx_out);

    const int total_waves  = BATCH * KK * CH * CW;          // 200,704
    const int blocks       = total_waves / 4;               // 50,176 (256 thr = 4 waves)
    crops_kernel<<<blocks, 256, 0, stream>>>(feature_map, boxes_out, crops_out);
}

// Round 3
// 271.714 us; speedup vs baseline: 1.1608x; 1.0063x over previous
//
#include <hip/hip_runtime.h>

#define BATCH 8
#define HH 64
#define WW 64
#define CC 256
#define KK 512
#define CH 7
#define CW 7
#define HW 4096            // HH*WW
#define CROPS_ELEMS (BATCH * KK * CH * CW * CC)   // 51,380,224
#define BOXES_ELEMS (BATCH * KK * 4)              // 16,384

using f4 = __attribute__((ext_vector_type(4))) float;

// ---------------------------------------------------------------------------
// Kernel 1: per-batch top-512 by RANK SELECTION (no sort, no cross-block
// sync). key = (ordered_uint(score) << 12) | (4095 - index) is unique per
// element, so rank(i) = #{keys > key_i} is the exact descending-sort position
// with jax.lax.top_k tie semantics (equal score -> lower index first).
// Grid: 512 blocks; batch = blockIdx % 8 (XCD-aligned so all 64 blocks of a
// batch share one XCD's L2 copy of the score row).
// ---------------------------------------------------------------------------
__global__ __launch_bounds__(256) void rank_topk_kernel(
    const float* __restrict__ scores,      // [B, 4096]
    const float* __restrict__ boxes,       // [B, 4096, 4]
    float* __restrict__ boxes_out,         // [B, 512, 4]
    float* __restrict__ idx_out)           // [B, 512] (as float values)
{
    __shared__ unsigned long long keys[HW];   // 32 KB
    __shared__ int cnt[64];

    const int b     = blockIdx.x & 7;         // batch -> XCD
    const int chunk = blockIdx.x >> 3;        // which 64-element slice we rank
    const int tid   = threadIdx.x;

    // Stage all 4096 keys of this batch into LDS (coalesced, 16/thread).
    for (int i = tid; i < HW; i += 256) {
        unsigned int u = __float_as_uint(scores[b * HW + i]);
        u = (u & 0x80000000u) ? ~u : (u | 0x80000000u);
        keys[i] = ((unsigned long long)u << 12) |
                  (unsigned long long)(HW - 1 - i);
    }
    if (tid < 64) cnt[tid] = 0;
    __syncthreads();

    // Element e = chunk*64 + (tid&63); this thread scans quarter (tid>>6).
    // LDS reads are wave-uniform (broadcast, conflict-free).
    const int e_local = tid & 63;
    const int e       = chunk * 64 + e_local;
    const unsigned long long mine = keys[e];
    const int seg = (tid >> 6) * (HW / 4);

    int c = 0;
    #pragma unroll 8
    for (int j = 0; j < HW / 4; ++j) {
        c += (keys[seg + j] > mine) ? 1 : 0;
    }
    atomicAdd(&cnt[e_local], c);
    __syncthreads();

    if (tid < 64) {
        const int r = cnt[tid];                 // exact descending rank
        if (r < KK) {
            const int i = chunk * 64 + tid;     // original flat index
            idx_out[b * KK + r] = (float)i;
            const float* bp = boxes + (size_t)(b * HW + i) * 4;
            float* op = boxes_out + (size_t)(b * KK + r) * 4;
            op[0] = bp[0]; op[1] = bp[1]; op[2] = bp[2]; op[3] = bp[3];
        }
    }
}

// ---------------------------------------------------------------------------
// Kernel 2: crop_and_resize. One wave per output pixel (b,n,iy,ix); each lane
// owns 4 channels (f4). 4 coalesced 1KiB gathers + blend + 1KiB NT store.
//
// XCD swizzle: batch = blockIdx % 8. Blocks dispatch round-robin over the 8
// XCDs, so each XCD's gathers hit only its batch's 4.19 MB fm slice — which
// fits that XCD's 4 MB L2 (vs. the whole 33.5 MB fm thrashing L2 and pushing
// 822 MB of gather traffic to the slower Infinity Cache). NT stores keep the
// streaming 205 MB output from evicting the fm.
//
// Coordinate math mirrors the reference's elementwise rounding exactly (no
// FMA contraction): floor() boundaries are discontinuous under the
// clip-after-floor edge semantics.
// ---------------------------------------------------------------------------
__global__ __launch_bounds__(256) void crops_kernel(
    const float* __restrict__ fm,          // [B, 64, 64, 256]
    const float* __restrict__ sboxes,      // [B, 512, 4]
    float* __restrict__ out)               // [B, 512, 7, 7, 256]
{
    const int b     = blockIdx.x & 7;              // batch -> XCD
    const int inner = blockIdx.x >> 3;             // 0..6271 within batch
    const int wib   = inner * 4 + (threadIdx.x >> 6);  // wave-in-batch: 0..25087
    const int lane  = threadIdx.x & 63;

    const int q  = wib % 49;               // iy*7 + ix
    const int n  = wib / 49;               // roi within batch
    const int iy = q / 7;
    const int ix = q % 7;
    const int bn = b * KK + n;

    const float* bp = sboxes + (size_t)bn * 4;
    const float y1 = bp[0], x1 = bp[1], y2 = bp[2], x2 = bp[3];

    const float fy = (float)iy / 6.0f;
    const float fx = (float)ix / 6.0f;
    // y = (y1 + fy*(y2-y1)) * 63 — exact elementwise rounding, no contraction
    const float y = __fmul_rn(__fadd_rn(y1, __fmul_rn(fy, __fsub_rn(y2, y1))), 63.0f);
    const float x = __fmul_rn(__fadd_rn(x1, __fmul_rn(fx, __fsub_rn(x2, x1))), 63.0f);

    const float y0f = floorf(y);
    const float x0f = floorf(x);
    const float wy = y - y0f;
    const float wx = x - x0f;

    int y0 = (int)y0f; y0 = min(max(y0, 0), HH - 1);
    int x0 = (int)x0f; x0 = min(max(x0, 0), WW - 1);
    const int y1i = min(y0 + 1, HH - 1);
    const int x1i = min(x0 + 1, WW - 1);

    const size_t base = (size_t)b * (HH * WW * CC);
    const int c0 = lane * 4;
    const f4 v00 = *(const f4*)(fm + base + (size_t)(y0  * WW + x0 ) * CC + c0);
    const f4 v01 = *(const f4*)(fm + base + (size_t)(y0  * WW + x1i) * CC + c0);
    const f4 v10 = *(const f4*)(fm + base + (size_t)(y1i * WW + x0 ) * CC + c0);
    const f4 v11 = *(const f4*)(fm + base + (size_t)(y1i * WW + x1i) * CC + c0);

    const float owx = 1.0f - wx;
    const float owy = 1.0f - wy;

    f4 r;
    #pragma unroll
    for (int k = 0; k < 4; ++k) {
        float t  = v00[k] * owx + v01[k] * wx;
        float bo = v10[k] * owx + v11[k] * wx;
        r[k] = t * owy + bo * wy;
    }

    __builtin_nontemporal_store(r, (f4*)(out + (size_t)(bn * 49 + q) * CC + c0));
}

extern "C" void kernel_launch(void* const* d_in, const int* in_sizes, int n_in,
                              void* d_out, int out_size, void* d_ws, size_t ws_size,
                              hipStream_t stream) {
    const float* feature_map = (const float*)d_in[0];   // 8*64*64*256
    const float* boxes       = (const float*)d_in[1];   // 8*64*64*4
    const float* rpn_loss    = (const float*)d_in[2];   // 8*64*64

    float* crops_out = (float*)d_out;                       // 51,380,224
    float* boxes_out = crops_out + CROPS_ELEMS;             // 16,384
    float* idx_out   = boxes_out + BOXES_ELEMS;             // 4,096

    rank_topk_kernel<<<BATCH * 64, 256, 0, stream>>>(rpn_loss, boxes, boxes_out, idx_out);

    const int total_waves  = BATCH * KK * CH * CW;          // 200,704
    const int blocks       = total_waves / 4;               // 50,176 (256 thr = 4 waves)
    crops_kernel<<<blocks, 256, 0, stream>>>(feature_map, boxes_out, crops_out);
}